// Round 15
// baseline (176.639 us; speedup 1.0000x reference)
//
#include <hip/hip_runtime.h>
#include <math.h>

using short8v = __attribute__((ext_vector_type(8))) short;
using f32x4   = __attribute__((ext_vector_type(4))) float;

constexpr int BCAP = 8192;  // per-bucket capacity (mean ~4081, >60 sigma headroom)

// ---------------- bf16 helpers ----------------

__device__ inline float bf_lo(unsigned int p) { return __uint_as_float(p << 16); }
__device__ inline float bf_hi(unsigned int p) { return __uint_as_float(p & 0xffff0000u); }
__device__ inline unsigned short f2bf(float f) {  // round-to-nearest-even
    unsigned int u = __float_as_uint(f);
    u += 0x7fffu + ((u >> 16) & 1u);
    return (unsigned short)(u >> 16);
}
__device__ inline unsigned int pack2bf(float a, float b) {
    return (unsigned int)f2bf(a) | ((unsigned int)f2bf(b) << 16);
}

// ------- prep: init bucket cursors + W1/W2 -> frag-major bf16 in global -------
// frag layout (per MFMA 16x16x32 B-operand): elem index e = ((c*KK+kk)*64 + l)*8 + j
// maps to W[kk*32 + (l>>4)*8 + j][c*16 + (l&15)].

__global__ __launch_bounds__(256)
void prep_kernel(const float* __restrict__ W1, const float* __restrict__ W2,
                 unsigned short* __restrict__ w1f, unsigned short* __restrict__ w2f,
                 int* __restrict__ bcur, int nb) {
    int i = blockIdx.x * 256 + threadIdx.x;
    if (i < nb) bcur[i] = i * BCAP;
    if (i < 8 * 2 * 64 * 8) {  // 8192 = K64 frags (KK=2)
        int j = i & 7, l = (i >> 3) & 63, rest = i >> 9;
        int kk = rest & 1, c = rest >> 1;
        int rk = kk * 32 + (l >> 4) * 8 + j;
        int cc = c * 16 + (l & 15);
        w1f[i] = f2bf(W1[rk * 128 + cc]);
    }
    if (i < 8 * 4 * 64 * 8) {  // 16384 = K128 frags (KK=4)
        int j = i & 7, l = (i >> 3) & 63, rest = i >> 9;
        int kk = rest & 3, c = rest >> 2;
        int rk = kk * 32 + (l >> 4) * 8 + j;
        int cc = c * 16 + (l & 15);
        w2f[i] = f2bf(W2[rk * 128 + cc]);
    }
}

// ---------------- partition: bucket edges by dst>>8; 4096 edges/block ----------------
// packed entry: (src << 8) | (dst & 255)   [valid: N < 65536]

__global__ __launch_bounds__(1024)
void partA_kernel(const int* __restrict__ src, const int* __restrict__ dst,
                  int* __restrict__ bcur, unsigned int* __restrict__ tmp, int E) {
    __shared__ int hist[256];
    __shared__ int chunk[256];
    int t = threadIdx.x;
    if (t < 256) hist[t] = 0;
    __syncthreads();
    int base = blockIdx.x * 4096;
    int s[4], d[4], bb[4], lr[4];
    bool val[4];
#pragma unroll
    for (int k = 0; k < 4; ++k) {
        int i = base + k * 1024 + t;
        val[k] = i < E;
        if (val[k]) {
            s[k] = src[i];
            d[k] = dst[i];
            bb[k] = d[k] >> 8;
            lr[k] = atomicAdd(&hist[bb[k]], 1);  // LDS: local rank in (block,bucket)
        }
    }
    __syncthreads();
    if (t < 256) {
        int c = hist[t];
        chunk[t] = (c > 0) ? atomicAdd(&bcur[t], c) : 0;
    }
    __syncthreads();
#pragma unroll
    for (int k = 0; k < 4; ++k) {
        if (val[k]) tmp[chunk[bb[k]] + lr[k]] = ((unsigned int)s[k] << 8) | (unsigned int)(d[k] & 255);
    }
}

// ------- bucket_build: folded bucket-scan + per-bucket CSR + dinv + prescaled z -------

__global__ __launch_bounds__(256)
void bucket_build_kernel(const unsigned int* __restrict__ tmp, const int* __restrict__ bcur,
                         const float* __restrict__ z, int* __restrict__ rowptr,
                         float* __restrict__ dinv, int* __restrict__ col,
                         unsigned int* __restrict__ zsb, int N, int nb, int E) {
    __shared__ int s[256];
    __shared__ int h[256];
    __shared__ int sc[256];
    __shared__ int cur[256];
    __shared__ float sdv[256];
    __shared__ int s_eb;
    int b = blockIdx.x;
    int t = threadIdx.x;
    // folded bscan: every block scans all bucket counts (196 ints, trivial)
    int cnt_t = (t < nb) ? (bcur[t] - t * BCAP) : 0;
    s[t] = cnt_t;
    __syncthreads();
    for (int off = 1; off < 256; off <<= 1) {
        int u = (t >= off) ? s[t - off] : 0;
        __syncthreads();
        s[t] += u;
        __syncthreads();
    }
    if (t == b) s_eb = s[t] - cnt_t;  // exclusive prefix for this bucket
    if (b == 0 && t == 0) rowptr[N] = E;
    h[t] = 0;
    __syncthreads();
    int eb = s_eb;
    int base = b * BCAP;
    int ecnt = bcur[b] - base;
    // per-node histogram
    for (int i = t; i < ecnt; i += 256) {
        atomicAdd(&h[tmp[base + i] & 255], 1);
    }
    __syncthreads();
    int v = h[t];
    sc[t] = v;
    __syncthreads();
    for (int off = 1; off < 256; off <<= 1) {
        int u = (t >= off) ? sc[t - off] : 0;
        __syncthreads();
        sc[t] += u;
        __syncthreads();
    }
    int excl = sc[t] - v;
    int nd = b * 256 + t;
    float dv = rsqrtf((float)v + 1.0f);  // degree incl. self-loop
    if (nd < N) {
        rowptr[nd] = eb + excl;
        dinv[nd] = dv;
    }
    sdv[t] = dv;
    cur[t] = excl;
    __syncthreads();
    // scatter col (LDS cursors, contiguous window)
    for (int i = t; i < ecnt; i += 256) {
        unsigned int e = tmp[base + i];
        int lpos = atomicAdd(&cur[e & 255], 1);
        col[eb + lpos] = (int)(e >> 8);
    }
    // prescale this block's 256 z-rows: zs = bf16(dinv * z), packed pairs (32 uints/row)
    int nd0 = b * 256;
    for (int idx = t; idx < 256 * 32; idx += 256) {
        int row = idx >> 5;
        int p = idx & 31;
        int node = nd0 + row;
        if (node < N) {
            float2 zv = ((const float2*)z)[(size_t)node * 32 + p];
            float d = sdv[row];
            zsb[(size_t)node * 32 + p] = pack2bf(d * zv.x, d * zv.y);
        }
    }
}

// ------- fused1: [agg64 over zs] -> LDS A-tile -> MFMA W1 -> hs = bf16(dinv.*relu(.+b1)) -------
// 4 waves/block, one 16-row tile per wave. A-tile row stride 36 uints (pad 16B -> 2-way banks).
// mfma_f32_16x16x32_bf16 frags: A lane l: row=l&15, k=(l>>4)*8+j ; B: col=l&15, k=(l>>4)*8+j ;
// C/D: col=l&15, row=(l>>4)*4+j  [m89-verified].

__global__ __launch_bounds__(256)
void fused1_kernel(const unsigned int* __restrict__ xs2, const int* __restrict__ rowptr,
                   const int* __restrict__ col, const float* __restrict__ dinv,
                   const unsigned short* __restrict__ w1f, const float* __restrict__ b1,
                   unsigned short* __restrict__ hsb, int n, int ntiles) {
    __shared__ unsigned int Atile[4][16][36];
    int t = threadIdx.x;
    int wv = t >> 6, lane = t & 63;
    int tile = blockIdx.x * 4 + wv;
    if (tile >= ntiles) tile = ntiles - 1;  // duplicate last tile (benign, keeps barrier uniform)
    int half = lane >> 5, sl = lane & 31;

    // Phase A: aggregate 16 rows into LDS A-tile (half-wave dual-edge gathers)
    for (int r = 0; r < 16; ++r) {
        int row = tile * 16 + r;
        float ax = 0.0f, ay = 0.0f;
        if (row < n) {
            int beg = rowptr[row];
            int end = rowptr[row + 1];
            float di = dinv[row];
            if (half == 0) {
                unsigned int sp = xs2[(size_t)row * 32 + sl];
                ax = bf_lo(sp);
                ay = bf_hi(sp);
            }
            int e = beg;
            for (; e + 7 < end; e += 8) {
                int c0 = col[e + half];
                int c1 = col[e + 2 + half];
                int c2 = col[e + 4 + half];
                int c3 = col[e + 6 + half];
                unsigned int p0 = xs2[(size_t)c0 * 32 + sl];
                unsigned int p1 = xs2[(size_t)c1 * 32 + sl];
                unsigned int p2 = xs2[(size_t)c2 * 32 + sl];
                unsigned int p3 = xs2[(size_t)c3 * 32 + sl];
                ax += bf_lo(p0); ay += bf_hi(p0);
                ax += bf_lo(p1); ay += bf_hi(p1);
                ax += bf_lo(p2); ay += bf_hi(p2);
                ax += bf_lo(p3); ay += bf_hi(p3);
            }
            for (; e < end; e += 2) {
                if (e + half < end) {
                    int c = col[e + half];
                    unsigned int p = xs2[(size_t)c * 32 + sl];
                    ax += bf_lo(p);
                    ay += bf_hi(p);
                }
            }
            ax += __shfl_xor(ax, 32);
            ay += __shfl_xor(ay, 32);
            ax *= di;
            ay *= di;
        }
        if (half == 0) Atile[wv][r][sl] = pack2bf(ax, ay);
    }
    __syncthreads();

    // Phase B: MFMA with frag-major W1 from global (L2-broadcast)
    const short8v* bfr = (const short8v*)w1f;
    const unsigned int* ap = &Atile[wv][0][0];
    short8v af[2];
#pragma unroll
    for (int kk = 0; kk < 2; ++kk) {
        af[kk] = *(const short8v*)(ap + (lane & 15) * 36 + kk * 16 + (lane >> 4) * 4);
    }
    f32x4 acc[8];
#pragma unroll
    for (int c = 0; c < 8; ++c) acc[c] = (f32x4){0.0f, 0.0f, 0.0f, 0.0f};
#pragma unroll
    for (int kk = 0; kk < 2; ++kk) {
#pragma unroll
        for (int c = 0; c < 8; ++c) {
            acc[c] = __builtin_amdgcn_mfma_f32_16x16x32_bf16(af[kk], bfr[(c * 2 + kk) * 64 + lane],
                                                             acc[c], 0, 0, 0);
        }
    }
    int colbase = lane & 15;
    int rowg = (lane >> 4) * 4;
    float dvj[4];
#pragma unroll
    for (int j = 0; j < 4; ++j) {
        int row = tile * 16 + rowg + j;
        dvj[j] = (row < n) ? dinv[row] : 1.0f;
    }
#pragma unroll
    for (int c = 0; c < 8; ++c) {
        float bv = b1[c * 16 + colbase];
#pragma unroll
        for (int j = 0; j < 4; ++j) {
            int row = tile * 16 + rowg + j;
            if (row < n) {
                float v = fmaxf(acc[c][j] + bv, 0.0f) * dvj[j];
                hsb[(size_t)row * 128 + c * 16 + colbase] = f2bf(v);
            }
        }
    }
}

// ------- fused2: [agg128 over hs] -> LDS A-tile -> MFMA W2 -> out fp32 (+b2) -------

__global__ __launch_bounds__(256)
void fused2_kernel(const unsigned int* __restrict__ hs2, const int* __restrict__ rowptr,
                   const int* __restrict__ col, const float* __restrict__ dinv,
                   const unsigned short* __restrict__ w2f, const float* __restrict__ b2,
                   float* __restrict__ out, int n, int ntiles) {
    __shared__ unsigned int Atile[4][16][68];
    int t = threadIdx.x;
    int wv = t >> 6, lane = t & 63;
    int tile = blockIdx.x * 4 + wv;
    if (tile >= ntiles) tile = ntiles - 1;

    // Phase A: aggregate 16 rows (full-wave, 1 uint = 2 feats per lane, 8-edge unroll)
    for (int r = 0; r < 16; ++r) {
        int row = tile * 16 + r;
        float ax = 0.0f, ay = 0.0f;
        if (row < n) {
            int beg = rowptr[row];
            int end = rowptr[row + 1];
            float di = dinv[row];
            unsigned int sp = hs2[(size_t)row * 64 + lane];
            ax = bf_lo(sp);
            ay = bf_hi(sp);
            int e = beg;
            for (; e + 7 < end; e += 8) {
                int c0 = col[e], c1 = col[e + 1], c2 = col[e + 2], c3 = col[e + 3];
                int c4 = col[e + 4], c5 = col[e + 5], c6 = col[e + 6], c7 = col[e + 7];
                unsigned int p0 = hs2[(size_t)c0 * 64 + lane];
                unsigned int p1 = hs2[(size_t)c1 * 64 + lane];
                unsigned int p2 = hs2[(size_t)c2 * 64 + lane];
                unsigned int p3 = hs2[(size_t)c3 * 64 + lane];
                unsigned int p4 = hs2[(size_t)c4 * 64 + lane];
                unsigned int p5 = hs2[(size_t)c5 * 64 + lane];
                unsigned int p6 = hs2[(size_t)c6 * 64 + lane];
                unsigned int p7 = hs2[(size_t)c7 * 64 + lane];
                ax += bf_lo(p0); ay += bf_hi(p0);
                ax += bf_lo(p1); ay += bf_hi(p1);
                ax += bf_lo(p2); ay += bf_hi(p2);
                ax += bf_lo(p3); ay += bf_hi(p3);
                ax += bf_lo(p4); ay += bf_hi(p4);
                ax += bf_lo(p5); ay += bf_hi(p5);
                ax += bf_lo(p6); ay += bf_hi(p6);
                ax += bf_lo(p7); ay += bf_hi(p7);
            }
            for (; e < end; ++e) {
                unsigned int p = hs2[(size_t)col[e] * 64 + lane];
                ax += bf_lo(p);
                ay += bf_hi(p);
            }
            ax *= di;
            ay *= di;
        }
        Atile[wv][r][lane] = pack2bf(ax, ay);
    }
    __syncthreads();

    // Phase B: MFMA with frag-major W2 from global
    const short8v* bfr = (const short8v*)w2f;
    const unsigned int* ap = &Atile[wv][0][0];
    short8v af[4];
#pragma unroll
    for (int kk = 0; kk < 4; ++kk) {
        af[kk] = *(const short8v*)(ap + (lane & 15) * 68 + kk * 16 + (lane >> 4) * 4);
    }
    f32x4 acc[8];
#pragma unroll
    for (int c = 0; c < 8; ++c) acc[c] = (f32x4){0.0f, 0.0f, 0.0f, 0.0f};
#pragma unroll
    for (int kk = 0; kk < 4; ++kk) {
#pragma unroll
        for (int c = 0; c < 8; ++c) {
            acc[c] = __builtin_amdgcn_mfma_f32_16x16x32_bf16(af[kk], bfr[(c * 4 + kk) * 64 + lane],
                                                             acc[c], 0, 0, 0);
        }
    }
    int colbase = lane & 15;
    int rowg = (lane >> 4) * 4;
#pragma unroll
    for (int c = 0; c < 8; ++c) {
        float bv = b2[c * 16 + colbase];
#pragma unroll
        for (int j = 0; j < 4; ++j) {
            int row = tile * 16 + rowg + j;
            if (row < n) {
                out[(size_t)row * 128 + c * 16 + colbase] = acc[c][j] + bv;
            }
        }
    }
}

// ---------------- launch ----------------

extern "C" void kernel_launch(void* const* d_in, const int* in_sizes, int n_in,
                              void* d_out, int out_size, void* d_ws, size_t ws_size,
                              hipStream_t stream) {
    const float* z  = (const float*)d_in[0];
    const int*   ei = (const int*)d_in[1];
    const float* W1 = (const float*)d_in[2];
    const float* b1 = (const float*)d_in[3];
    const float* W2 = (const float*)d_in[4];
    const float* b2 = (const float*)d_in[5];
    float* out = (float*)d_out;

    int N = in_sizes[0] / 64;
    int E = in_sizes[1] / 2;
    const int* srcp = ei;
    const int* dstp = ei + E;

    char* w = (char*)d_ws;
    auto alloc = [&](size_t bytes) -> char* {
        char* p = w;
        w += (bytes + 255) & ~(size_t)255;
        return p;
    };
    int nb = (N + 255) / 256;  // 196 for N=50000 (must be <= 256)

    int*   rowptr = (int*)alloc((size_t)(N + 1) * 4);
    float* dinv   = (float*)alloc((size_t)N * 4);
    int*   bcur   = (int*)alloc((size_t)nb * 4);
    int*   col    = (int*)alloc((size_t)E * 4);
    unsigned int* tmp = (unsigned int*)alloc((size_t)nb * BCAP * 4);  // packed (src<<8)|(dst&255)
    unsigned int*   zsb = (unsigned int*)alloc((size_t)N * 64 * 2);   // bf16 zs = dinv*z (packed)
    unsigned short* hsb = (unsigned short*)alloc((size_t)N * 128 * 2);// bf16 hs = dinv*h
    unsigned short* w1f = (unsigned short*)alloc(8192 * 2);           // W1 frag-major bf16
    unsigned short* w2f = (unsigned short*)alloc(16384 * 2);          // W2 frag-major bf16

    int ntiles = (N + 15) / 16;           // 3125 for N=50000
    int fusedBlocks = (ntiles + 3) / 4;   // 4 waves (tiles) per block

    // 5 dispatches total
    prep_kernel<<<64, 256, 0, stream>>>(W1, W2, w1f, w2f, bcur, nb);
    partA_kernel<<<(E + 4095) / 4096, 1024, 0, stream>>>(srcp, dstp, bcur, tmp, E);
    bucket_build_kernel<<<nb, 256, 0, stream>>>(tmp, bcur, z, rowptr, dinv, col, zsb, N, nb, E);
    fused1_kernel<<<fusedBlocks, 256, 0, stream>>>(zsb, rowptr, col, dinv, w1f, b1, hsb, N, ntiles);
    fused2_kernel<<<fusedBlocks, 256, 0, stream>>>((const unsigned int*)hsb, rowptr, col, dinv,
                                                   w2f, b2, out, N, ntiles);
}

// Round 16
// 122.785 us; speedup vs baseline: 1.4386x; 1.4386x over previous
//
#include <hip/hip_runtime.h>
#include <math.h>

using short8v = __attribute__((ext_vector_type(8))) short;
using f32x4   = __attribute__((ext_vector_type(4))) float;

constexpr int BCAP = 8192;  // per-bucket capacity (mean ~4081, >60 sigma headroom)

// ---------------- bf16 helpers ----------------

__device__ inline float bf_lo(unsigned int p) { return __uint_as_float(p << 16); }
__device__ inline float bf_hi(unsigned int p) { return __uint_as_float(p & 0xffff0000u); }
__device__ inline unsigned short f2bf(float f) {  // round-to-nearest-even
    unsigned int u = __float_as_uint(f);
    u += 0x7fffu + ((u >> 16) & 1u);
    return (unsigned short)(u >> 16);
}
__device__ inline unsigned int pack2bf(float a, float b) {
    return (unsigned int)f2bf(a) | ((unsigned int)f2bf(b) << 16);
}

// ------- prep: init bucket cursors + W1/W2 -> frag-major bf16 in global -------
// frag layout (per MFMA 16x16x32 B-operand): elem index e = ((c*KK+kk)*64 + l)*8 + j
// maps to W[kk*32 + (l>>4)*8 + j][c*16 + (l&15)].

__global__ __launch_bounds__(256)
void prep_kernel(const float* __restrict__ W1, const float* __restrict__ W2,
                 unsigned short* __restrict__ w1f, unsigned short* __restrict__ w2f,
                 int* __restrict__ bcur, int nb) {
    int i = blockIdx.x * 256 + threadIdx.x;
    if (i < nb) bcur[i] = i * BCAP;
    if (i < 8 * 2 * 64 * 8) {  // 8192 = K64 frags (KK=2)
        int j = i & 7, l = (i >> 3) & 63, rest = i >> 9;
        int kk = rest & 1, c = rest >> 1;
        int rk = kk * 32 + (l >> 4) * 8 + j;
        int cc = c * 16 + (l & 15);
        w1f[i] = f2bf(W1[rk * 128 + cc]);
    }
    if (i < 8 * 4 * 64 * 8) {  // 16384 = K128 frags (KK=4)
        int j = i & 7, l = (i >> 3) & 63, rest = i >> 9;
        int kk = rest & 3, c = rest >> 2;
        int rk = kk * 32 + (l >> 4) * 8 + j;
        int cc = c * 16 + (l & 15);
        w2f[i] = f2bf(W2[rk * 128 + cc]);
    }
}

// ---------------- partition: bucket edges by dst>>8; 4096 edges/block ----------------
// packed entry: (src << 8) | (dst & 255)   [valid: N < 65536]

__global__ __launch_bounds__(1024)
void partA_kernel(const int* __restrict__ src, const int* __restrict__ dst,
                  int* __restrict__ bcur, unsigned int* __restrict__ tmp, int E) {
    __shared__ int hist[256];
    __shared__ int chunk[256];
    int t = threadIdx.x;
    if (t < 256) hist[t] = 0;
    __syncthreads();
    int base = blockIdx.x * 4096;
    int s[4], d[4], bb[4], lr[4];
    bool val[4];
#pragma unroll
    for (int k = 0; k < 4; ++k) {
        int i = base + k * 1024 + t;
        val[k] = i < E;
        if (val[k]) {
            s[k] = src[i];
            d[k] = dst[i];
            bb[k] = d[k] >> 8;
            lr[k] = atomicAdd(&hist[bb[k]], 1);  // LDS: local rank in (block,bucket)
        }
    }
    __syncthreads();
    if (t < 256) {
        int c = hist[t];
        chunk[t] = (c > 0) ? atomicAdd(&bcur[t], c) : 0;
    }
    __syncthreads();
#pragma unroll
    for (int k = 0; k < 4; ++k) {
        if (val[k]) tmp[chunk[bb[k]] + lr[k]] = ((unsigned int)s[k] << 8) | (unsigned int)(d[k] & 255);
    }
}

// ------- bucket_build: folded bucket-scan + per-bucket CSR + dinv + prescaled z -------

__global__ __launch_bounds__(256)
void bucket_build_kernel(const unsigned int* __restrict__ tmp, const int* __restrict__ bcur,
                         const float* __restrict__ z, int* __restrict__ rowptr,
                         float* __restrict__ dinv, int* __restrict__ col,
                         unsigned int* __restrict__ zsb, int N, int nb, int E) {
    __shared__ int s[256];
    __shared__ int h[256];
    __shared__ int sc[256];
    __shared__ int cur[256];
    __shared__ float sdv[256];
    __shared__ int s_eb;
    int b = blockIdx.x;
    int t = threadIdx.x;
    // folded bscan: every block scans all bucket counts (196 ints, trivial)
    int cnt_t = (t < nb) ? (bcur[t] - t * BCAP) : 0;
    s[t] = cnt_t;
    __syncthreads();
    for (int off = 1; off < 256; off <<= 1) {
        int u = (t >= off) ? s[t - off] : 0;
        __syncthreads();
        s[t] += u;
        __syncthreads();
    }
    if (t == b) s_eb = s[t] - cnt_t;  // exclusive prefix for this bucket
    if (b == 0 && t == 0) rowptr[N] = E;
    h[t] = 0;
    __syncthreads();
    int eb = s_eb;
    int base = b * BCAP;
    int ecnt = bcur[b] - base;
    // per-node histogram
    for (int i = t; i < ecnt; i += 256) {
        atomicAdd(&h[tmp[base + i] & 255], 1);
    }
    __syncthreads();
    int v = h[t];
    sc[t] = v;
    __syncthreads();
    for (int off = 1; off < 256; off <<= 1) {
        int u = (t >= off) ? sc[t - off] : 0;
        __syncthreads();
        sc[t] += u;
        __syncthreads();
    }
    int excl = sc[t] - v;
    int nd = b * 256 + t;
    float dv = rsqrtf((float)v + 1.0f);  // degree incl. self-loop
    if (nd < N) {
        rowptr[nd] = eb + excl;
        dinv[nd] = dv;
    }
    sdv[t] = dv;
    cur[t] = excl;
    __syncthreads();
    // scatter col (LDS cursors, contiguous window)
    for (int i = t; i < ecnt; i += 256) {
        unsigned int e = tmp[base + i];
        int lpos = atomicAdd(&cur[e & 255], 1);
        col[eb + lpos] = (int)(e >> 8);
    }
    // prescale this block's 256 z-rows: zs = bf16(dinv * z), packed pairs (32 uints/row)
    int nd0 = b * 256;
    for (int idx = t; idx < 256 * 32; idx += 256) {
        int row = idx >> 5;
        int p = idx & 31;
        int node = nd0 + row;
        if (node < N) {
            float2 zv = ((const float2*)z)[(size_t)node * 32 + p];
            float d = sdv[row];
            zsb[(size_t)node * 32 + p] = pack2bf(d * zv.x, d * zv.y);
        }
    }
}

// ------- fused1: [agg64 over zs] -> LDS A-tile -> MFMA W1 -> hs = bf16(dinv.*relu(.+b1)) -------
// ONE 16-row tile per 256-thread block (grid = ntiles = 3125 -> full occupancy).
// Phase A: each of 4 waves aggregates 4 rows (half-wave dual-edge gathers).
// Phase B: each wave computes a 16x32 column slice (c-frags wv*2, wv*2+1).
// mfma_f32_16x16x32_bf16 frags: A lane l: row=l&15, k=(l>>4)*8+j ; B: col=l&15, k=(l>>4)*8+j ;
// C/D: col=l&15, row=(l>>4)*4+j  [m89-verified].

__global__ __launch_bounds__(256)
void fused1_kernel(const unsigned int* __restrict__ xs2, const int* __restrict__ rowptr,
                   const int* __restrict__ col, const float* __restrict__ dinv,
                   const unsigned short* __restrict__ w1f, const float* __restrict__ b1,
                   unsigned short* __restrict__ hsb, int n) {
    __shared__ unsigned int Atile[16][36];  // row-stride 36 uints (16B pad -> 2-way banks)
    int t = threadIdx.x;
    int wv = t >> 6, lane = t & 63;
    int tile = blockIdx.x;
    int half = lane >> 5, sl = lane & 31;

    // Phase A: 4 rows per wave
    for (int rr = 0; rr < 4; ++rr) {
        int r = wv * 4 + rr;
        int row = tile * 16 + r;
        float ax = 0.0f, ay = 0.0f;
        if (row < n) {
            int beg = rowptr[row];
            int end = rowptr[row + 1];
            float di = dinv[row];
            if (half == 0) {
                unsigned int sp = xs2[(size_t)row * 32 + sl];
                ax = bf_lo(sp);
                ay = bf_hi(sp);
            }
            int e = beg;
            for (; e + 7 < end; e += 8) {
                int c0 = col[e + half];
                int c1 = col[e + 2 + half];
                int c2 = col[e + 4 + half];
                int c3 = col[e + 6 + half];
                unsigned int p0 = xs2[(size_t)c0 * 32 + sl];
                unsigned int p1 = xs2[(size_t)c1 * 32 + sl];
                unsigned int p2 = xs2[(size_t)c2 * 32 + sl];
                unsigned int p3 = xs2[(size_t)c3 * 32 + sl];
                ax += bf_lo(p0); ay += bf_hi(p0);
                ax += bf_lo(p1); ay += bf_hi(p1);
                ax += bf_lo(p2); ay += bf_hi(p2);
                ax += bf_lo(p3); ay += bf_hi(p3);
            }
            for (; e < end; e += 2) {
                if (e + half < end) {
                    int c = col[e + half];
                    unsigned int p = xs2[(size_t)c * 32 + sl];
                    ax += bf_lo(p);
                    ay += bf_hi(p);
                }
            }
            ax += __shfl_xor(ax, 32);
            ay += __shfl_xor(ay, 32);
            ax *= di;
            ay *= di;
        }
        if (half == 0) Atile[r][sl] = pack2bf(ax, ay);
    }
    __syncthreads();

    // Phase B: wave wv computes cols [wv*32, wv*32+32) = c-frags {wv*2, wv*2+1}
    const short8v* bfr = (const short8v*)w1f;
    const unsigned int* ap = &Atile[0][0];
    short8v af[2];
#pragma unroll
    for (int kk = 0; kk < 2; ++kk) {
        af[kk] = *(const short8v*)(ap + (lane & 15) * 36 + kk * 16 + (lane >> 4) * 4);
    }
    f32x4 acc[2];
#pragma unroll
    for (int ci = 0; ci < 2; ++ci) acc[ci] = (f32x4){0.0f, 0.0f, 0.0f, 0.0f};
#pragma unroll
    for (int kk = 0; kk < 2; ++kk) {
#pragma unroll
        for (int ci = 0; ci < 2; ++ci) {
            int c = wv * 2 + ci;
            acc[ci] = __builtin_amdgcn_mfma_f32_16x16x32_bf16(af[kk], bfr[(c * 2 + kk) * 64 + lane],
                                                              acc[ci], 0, 0, 0);
        }
    }
    int colbase = lane & 15;
    int rowg = (lane >> 4) * 4;
    float dvj[4];
#pragma unroll
    for (int j = 0; j < 4; ++j) {
        int row = tile * 16 + rowg + j;
        dvj[j] = (row < n) ? dinv[row] : 1.0f;
    }
#pragma unroll
    for (int ci = 0; ci < 2; ++ci) {
        int c = wv * 2 + ci;
        float bv = b1[c * 16 + colbase];
#pragma unroll
        for (int j = 0; j < 4; ++j) {
            int row = tile * 16 + rowg + j;
            if (row < n) {
                float v = fmaxf(acc[ci][j] + bv, 0.0f) * dvj[j];
                hsb[(size_t)row * 128 + c * 16 + colbase] = f2bf(v);
            }
        }
    }
}

// ------- fused2: [agg128 over hs] -> LDS A-tile -> MFMA W2 -> out fp32 (+b2) -------
// Same decomposition: 1 tile/block, 4 rows/wave aggregation, 16x32 slice/wave MFMA.

__global__ __launch_bounds__(256)
void fused2_kernel(const unsigned int* __restrict__ hs2, const int* __restrict__ rowptr,
                   const int* __restrict__ col, const float* __restrict__ dinv,
                   const unsigned short* __restrict__ w2f, const float* __restrict__ b2,
                   float* __restrict__ out, int n) {
    __shared__ unsigned int Atile[16][68];  // row-stride 68 uints (16B pad)
    int t = threadIdx.x;
    int wv = t >> 6, lane = t & 63;
    int tile = blockIdx.x;

    // Phase A: 4 rows per wave (full-wave, 1 uint = 2 feats per lane, 8-edge unroll)
    for (int rr = 0; rr < 4; ++rr) {
        int r = wv * 4 + rr;
        int row = tile * 16 + r;
        float ax = 0.0f, ay = 0.0f;
        if (row < n) {
            int beg = rowptr[row];
            int end = rowptr[row + 1];
            float di = dinv[row];
            unsigned int sp = hs2[(size_t)row * 64 + lane];
            ax = bf_lo(sp);
            ay = bf_hi(sp);
            int e = beg;
            for (; e + 7 < end; e += 8) {
                int c0 = col[e], c1 = col[e + 1], c2 = col[e + 2], c3 = col[e + 3];
                int c4 = col[e + 4], c5 = col[e + 5], c6 = col[e + 6], c7 = col[e + 7];
                unsigned int p0 = hs2[(size_t)c0 * 64 + lane];
                unsigned int p1 = hs2[(size_t)c1 * 64 + lane];
                unsigned int p2 = hs2[(size_t)c2 * 64 + lane];
                unsigned int p3 = hs2[(size_t)c3 * 64 + lane];
                unsigned int p4 = hs2[(size_t)c4 * 64 + lane];
                unsigned int p5 = hs2[(size_t)c5 * 64 + lane];
                unsigned int p6 = hs2[(size_t)c6 * 64 + lane];
                unsigned int p7 = hs2[(size_t)c7 * 64 + lane];
                ax += bf_lo(p0); ay += bf_hi(p0);
                ax += bf_lo(p1); ay += bf_hi(p1);
                ax += bf_lo(p2); ay += bf_hi(p2);
                ax += bf_lo(p3); ay += bf_hi(p3);
                ax += bf_lo(p4); ay += bf_hi(p4);
                ax += bf_lo(p5); ay += bf_hi(p5);
                ax += bf_lo(p6); ay += bf_hi(p6);
                ax += bf_lo(p7); ay += bf_hi(p7);
            }
            for (; e < end; ++e) {
                unsigned int p = hs2[(size_t)col[e] * 64 + lane];
                ax += bf_lo(p);
                ay += bf_hi(p);
            }
            ax *= di;
            ay *= di;
        }
        Atile[r][lane] = pack2bf(ax, ay);
    }
    __syncthreads();

    // Phase B: wave wv computes cols [wv*32, wv*32+32) = c-frags {wv*2, wv*2+1}
    const short8v* bfr = (const short8v*)w2f;
    const unsigned int* ap = &Atile[0][0];
    short8v af[4];
#pragma unroll
    for (int kk = 0; kk < 4; ++kk) {
        af[kk] = *(const short8v*)(ap + (lane & 15) * 68 + kk * 16 + (lane >> 4) * 4);
    }
    f32x4 acc[2];
#pragma unroll
    for (int ci = 0; ci < 2; ++ci) acc[ci] = (f32x4){0.0f, 0.0f, 0.0f, 0.0f};
#pragma unroll
    for (int kk = 0; kk < 4; ++kk) {
#pragma unroll
        for (int ci = 0; ci < 2; ++ci) {
            int c = wv * 2 + ci;
            acc[ci] = __builtin_amdgcn_mfma_f32_16x16x32_bf16(af[kk], bfr[(c * 4 + kk) * 64 + lane],
                                                              acc[ci], 0, 0, 0);
        }
    }
    int colbase = lane & 15;
    int rowg = (lane >> 4) * 4;
#pragma unroll
    for (int ci = 0; ci < 2; ++ci) {
        int c = wv * 2 + ci;
        float bv = b2[c * 16 + colbase];
#pragma unroll
        for (int j = 0; j < 4; ++j) {
            int row = tile * 16 + rowg + j;
            if (row < n) {
                out[(size_t)row * 128 + c * 16 + colbase] = acc[ci][j] + bv;
            }
        }
    }
}

// ---------------- launch ----------------

extern "C" void kernel_launch(void* const* d_in, const int* in_sizes, int n_in,
                              void* d_out, int out_size, void* d_ws, size_t ws_size,
                              hipStream_t stream) {
    const float* z  = (const float*)d_in[0];
    const int*   ei = (const int*)d_in[1];
    const float* W1 = (const float*)d_in[2];
    const float* b1 = (const float*)d_in[3];
    const float* W2 = (const float*)d_in[4];
    const float* b2 = (const float*)d_in[5];
    float* out = (float*)d_out;

    int N = in_sizes[0] / 64;
    int E = in_sizes[1] / 2;
    const int* srcp = ei;
    const int* dstp = ei + E;

    char* w = (char*)d_ws;
    auto alloc = [&](size_t bytes) -> char* {
        char* p = w;
        w += (bytes + 255) & ~(size_t)255;
        return p;
    };
    int nb = (N + 255) / 256;  // 196 for N=50000 (must be <= 256)

    int*   rowptr = (int*)alloc((size_t)(N + 1) * 4);
    float* dinv   = (float*)alloc((size_t)N * 4);
    int*   bcur   = (int*)alloc((size_t)nb * 4);
    int*   col    = (int*)alloc((size_t)E * 4);
    unsigned int* tmp = (unsigned int*)alloc((size_t)nb * BCAP * 4);  // packed (src<<8)|(dst&255)
    unsigned int*   zsb = (unsigned int*)alloc((size_t)N * 64 * 2);   // bf16 zs = dinv*z (packed)
    unsigned short* hsb = (unsigned short*)alloc((size_t)N * 128 * 2);// bf16 hs = dinv*h
    unsigned short* w1f = (unsigned short*)alloc(8192 * 2);           // W1 frag-major bf16
    unsigned short* w2f = (unsigned short*)alloc(16384 * 2);          // W2 frag-major bf16

    int ntiles = (N + 15) / 16;  // 3125 for N=50000

    // 5 dispatches total
    prep_kernel<<<64, 256, 0, stream>>>(W1, W2, w1f, w2f, bcur, nb);
    partA_kernel<<<(E + 4095) / 4096, 1024, 0, stream>>>(srcp, dstp, bcur, tmp, E);
    bucket_build_kernel<<<nb, 256, 0, stream>>>(tmp, bcur, z, rowptr, dinv, col, zsb, N, nb, E);
    fused1_kernel<<<ntiles, 256, 0, stream>>>(zsb, rowptr, col, dinv, w1f, b1, hsb, N);
    fused2_kernel<<<ntiles, 256, 0, stream>>>((const unsigned int*)hsb, rowptr, col, dinv,
                                              w2f, b2, out, N);
}

// Round 17
// 113.498 us; speedup vs baseline: 1.5563x; 1.0818x over previous
//
#include <hip/hip_runtime.h>
#include <math.h>

using short8v = __attribute__((ext_vector_type(8))) short;
using f32x4   = __attribute__((ext_vector_type(4))) float;

constexpr int BCAP = 8192;  // per-bucket capacity (mean ~4081, >60 sigma headroom)

// ---------------- bf16 helpers ----------------

__device__ inline float bf_lo(unsigned int p) { return __uint_as_float(p << 16); }
__device__ inline float bf_hi(unsigned int p) { return __uint_as_float(p & 0xffff0000u); }
__device__ inline unsigned short f2bf(float f) {  // round-to-nearest-even
    unsigned int u = __float_as_uint(f);
    u += 0x7fffu + ((u >> 16) & 1u);
    return (unsigned short)(u >> 16);
}
__device__ inline unsigned int pack2bf(float a, float b) {
    return (unsigned int)f2bf(a) | ((unsigned int)f2bf(b) << 16);
}

// ------- prep: init bucket cursors + W1/W2 -> frag-major bf16 in global -------
// frag layout (per MFMA 16x16x32 B-operand): elem index e = ((c*KK+kk)*64 + l)*8 + j
// maps to W[kk*32 + (l>>4)*8 + j][c*16 + (l&15)].

__global__ __launch_bounds__(256)
void prep_kernel(const float* __restrict__ W1, const float* __restrict__ W2,
                 unsigned short* __restrict__ w1f, unsigned short* __restrict__ w2f,
                 int* __restrict__ bcur, int nb) {
    int i = blockIdx.x * 256 + threadIdx.x;
    if (i < nb) bcur[i] = i * BCAP;
    if (i < 8 * 2 * 64 * 8) {  // 8192 = K64 frags (KK=2)
        int j = i & 7, l = (i >> 3) & 63, rest = i >> 9;
        int kk = rest & 1, c = rest >> 1;
        int rk = kk * 32 + (l >> 4) * 8 + j;
        int cc = c * 16 + (l & 15);
        w1f[i] = f2bf(W1[rk * 128 + cc]);
    }
    if (i < 8 * 4 * 64 * 8) {  // 16384 = K128 frags (KK=4)
        int j = i & 7, l = (i >> 3) & 63, rest = i >> 9;
        int kk = rest & 3, c = rest >> 2;
        int rk = kk * 32 + (l >> 4) * 8 + j;
        int cc = c * 16 + (l & 15);
        w2f[i] = f2bf(W2[rk * 128 + cc]);
    }
}

// ---------------- partition: bucket edges by dst>>8; 4096 edges/block ----------------
// packed entry: (src << 8) | (dst & 255)   [valid: N < 65536]

__global__ __launch_bounds__(1024)
void partA_kernel(const int* __restrict__ src, const int* __restrict__ dst,
                  int* __restrict__ bcur, unsigned int* __restrict__ tmp, int E) {
    __shared__ int hist[256];
    __shared__ int chunk[256];
    int t = threadIdx.x;
    if (t < 256) hist[t] = 0;
    __syncthreads();
    int base = blockIdx.x * 4096;
    int s[4], d[4], bb[4], lr[4];
    bool val[4];
#pragma unroll
    for (int k = 0; k < 4; ++k) {
        int i = base + k * 1024 + t;
        val[k] = i < E;
        if (val[k]) {
            s[k] = src[i];
            d[k] = dst[i];
            bb[k] = d[k] >> 8;
            lr[k] = atomicAdd(&hist[bb[k]], 1);  // LDS: local rank in (block,bucket)
        }
    }
    __syncthreads();
    if (t < 256) {
        int c = hist[t];
        chunk[t] = (c > 0) ? atomicAdd(&bcur[t], c) : 0;
    }
    __syncthreads();
#pragma unroll
    for (int k = 0; k < 4; ++k) {
        if (val[k]) tmp[chunk[bb[k]] + lr[k]] = ((unsigned int)s[k] << 8) | (unsigned int)(d[k] & 255);
    }
}

// ------- bucket_build: folded bucket-scan + per-bucket CSR + dinv + prescaled z -------

__global__ __launch_bounds__(256)
void bucket_build_kernel(const unsigned int* __restrict__ tmp, const int* __restrict__ bcur,
                         const float* __restrict__ z, int* __restrict__ rowptr,
                         float* __restrict__ dinv, int* __restrict__ col,
                         unsigned int* __restrict__ zsb, int N, int nb, int E) {
    __shared__ int s[256];
    __shared__ int h[256];
    __shared__ int sc[256];
    __shared__ int cur[256];
    __shared__ float sdv[256];
    __shared__ int s_eb;
    int b = blockIdx.x;
    int t = threadIdx.x;
    // folded bscan: every block scans all bucket counts (196 ints, trivial)
    int cnt_t = (t < nb) ? (bcur[t] - t * BCAP) : 0;
    s[t] = cnt_t;
    __syncthreads();
    for (int off = 1; off < 256; off <<= 1) {
        int u = (t >= off) ? s[t - off] : 0;
        __syncthreads();
        s[t] += u;
        __syncthreads();
    }
    if (t == b) s_eb = s[t] - cnt_t;  // exclusive prefix for this bucket
    if (b == 0 && t == 0) rowptr[N] = E;
    h[t] = 0;
    __syncthreads();
    int eb = s_eb;
    int base = b * BCAP;
    int ecnt = bcur[b] - base;
    // per-node histogram
    for (int i = t; i < ecnt; i += 256) {
        atomicAdd(&h[tmp[base + i] & 255], 1);
    }
    __syncthreads();
    int v = h[t];
    sc[t] = v;
    __syncthreads();
    for (int off = 1; off < 256; off <<= 1) {
        int u = (t >= off) ? sc[t - off] : 0;
        __syncthreads();
        sc[t] += u;
        __syncthreads();
    }
    int excl = sc[t] - v;
    int nd = b * 256 + t;
    float dv = rsqrtf((float)v + 1.0f);  // degree incl. self-loop
    if (nd < N) {
        rowptr[nd] = eb + excl;
        dinv[nd] = dv;
    }
    sdv[t] = dv;
    cur[t] = excl;
    __syncthreads();
    // scatter col (LDS cursors, contiguous window)
    for (int i = t; i < ecnt; i += 256) {
        unsigned int e = tmp[base + i];
        int lpos = atomicAdd(&cur[e & 255], 1);
        col[eb + lpos] = (int)(e >> 8);
    }
    // prescale this block's 256 z-rows: zs = bf16(dinv * z), packed pairs (32 uints/row)
    int nd0 = b * 256;
    for (int idx = t; idx < 256 * 32; idx += 256) {
        int row = idx >> 5;
        int p = idx & 31;
        int node = nd0 + row;
        if (node < N) {
            float2 zv = ((const float2*)z)[(size_t)node * 32 + p];
            float d = sdv[row];
            zsb[(size_t)node * 32 + p] = pack2bf(d * zv.x, d * zv.y);
        }
    }
}

// ------- fused1: [agg64 over zs] -> LDS A-tile -> MFMA W1 -> hs = bf16(dinv.*relu(.+b1)) -------
// 1 tile (16 rows) per 256-thread block. Phase A: HALF-WAVE PER ROW (32 lanes x uint = 128 B row),
// 2 rows in flight per wave x 8-edge unroll = ~16 outstanding gathers; 2 passes cover 4 rows/wave.
// No shfl merge: each half-wave holds its full row sum. Phase B: 16x32 col slice per wave.
// mfma_f32_16x16x32_bf16 frags: A lane l: row=l&15, k=(l>>4)*8+j ; B: col=l&15, k=(l>>4)*8+j ;
// C/D: col=l&15, row=(l>>4)*4+j  [m89-verified].

__global__ __launch_bounds__(256)
void fused1_kernel(const unsigned int* __restrict__ xs2, const int* __restrict__ rowptr,
                   const int* __restrict__ col, const float* __restrict__ dinv,
                   const unsigned short* __restrict__ w1f, const float* __restrict__ b1,
                   unsigned short* __restrict__ hsb, int n) {
    __shared__ unsigned int Atile[16][36];  // row-stride 36 uints (16B pad -> 2-way banks)
    int t = threadIdx.x;
    int wv = t >> 6, lane = t & 63;
    int tile = blockIdx.x;
    int half = lane >> 5, sl = lane & 31;

    // Phase A: 2 passes x (2 rows per wave, one per half-wave)
#pragma unroll
    for (int pass = 0; pass < 2; ++pass) {
        int r = wv * 4 + pass * 2 + half;
        int row = tile * 16 + r;
        float ax = 0.0f, ay = 0.0f;
        if (row < n) {
            int beg = rowptr[row];
            int end = rowptr[row + 1];
            float di = dinv[row];
            unsigned int sp = xs2[(size_t)row * 32 + sl];
            ax = bf_lo(sp);
            ay = bf_hi(sp);
            int e = beg;
            for (; e + 7 < end; e += 8) {
                int c0 = col[e], c1 = col[e + 1], c2 = col[e + 2], c3 = col[e + 3];
                int c4 = col[e + 4], c5 = col[e + 5], c6 = col[e + 6], c7 = col[e + 7];
                unsigned int p0 = xs2[(size_t)c0 * 32 + sl];
                unsigned int p1 = xs2[(size_t)c1 * 32 + sl];
                unsigned int p2 = xs2[(size_t)c2 * 32 + sl];
                unsigned int p3 = xs2[(size_t)c3 * 32 + sl];
                unsigned int p4 = xs2[(size_t)c4 * 32 + sl];
                unsigned int p5 = xs2[(size_t)c5 * 32 + sl];
                unsigned int p6 = xs2[(size_t)c6 * 32 + sl];
                unsigned int p7 = xs2[(size_t)c7 * 32 + sl];
                ax += bf_lo(p0); ay += bf_hi(p0);
                ax += bf_lo(p1); ay += bf_hi(p1);
                ax += bf_lo(p2); ay += bf_hi(p2);
                ax += bf_lo(p3); ay += bf_hi(p3);
                ax += bf_lo(p4); ay += bf_hi(p4);
                ax += bf_lo(p5); ay += bf_hi(p5);
                ax += bf_lo(p6); ay += bf_hi(p6);
                ax += bf_lo(p7); ay += bf_hi(p7);
            }
            for (; e < end; ++e) {
                int c = col[e];
                unsigned int p = xs2[(size_t)c * 32 + sl];
                ax += bf_lo(p);
                ay += bf_hi(p);
            }
            ax *= di;
            ay *= di;
        }
        Atile[r][sl] = pack2bf(ax, ay);
    }
    __syncthreads();

    // Phase B: wave wv computes cols [wv*32, wv*32+32) = c-frags {wv*2, wv*2+1}
    const short8v* bfr = (const short8v*)w1f;
    const unsigned int* ap = &Atile[0][0];
    short8v af[2];
#pragma unroll
    for (int kk = 0; kk < 2; ++kk) {
        af[kk] = *(const short8v*)(ap + (lane & 15) * 36 + kk * 16 + (lane >> 4) * 4);
    }
    f32x4 acc[2];
#pragma unroll
    for (int ci = 0; ci < 2; ++ci) acc[ci] = (f32x4){0.0f, 0.0f, 0.0f, 0.0f};
#pragma unroll
    for (int kk = 0; kk < 2; ++kk) {
#pragma unroll
        for (int ci = 0; ci < 2; ++ci) {
            int c = wv * 2 + ci;
            acc[ci] = __builtin_amdgcn_mfma_f32_16x16x32_bf16(af[kk], bfr[(c * 2 + kk) * 64 + lane],
                                                              acc[ci], 0, 0, 0);
        }
    }
    int colbase = lane & 15;
    int rowg = (lane >> 4) * 4;
    float dvj[4];
#pragma unroll
    for (int j = 0; j < 4; ++j) {
        int row = tile * 16 + rowg + j;
        dvj[j] = (row < n) ? dinv[row] : 1.0f;
    }
#pragma unroll
    for (int ci = 0; ci < 2; ++ci) {
        int c = wv * 2 + ci;
        float bv = b1[c * 16 + colbase];
#pragma unroll
        for (int j = 0; j < 4; ++j) {
            int row = tile * 16 + rowg + j;
            if (row < n) {
                float v = fmaxf(acc[ci][j] + bv, 0.0f) * dvj[j];
                hsb[(size_t)row * 128 + c * 16 + colbase] = f2bf(v);
            }
        }
    }
}

// ------- fused2: [agg128 over hs] -> LDS A-tile -> MFMA W2 -> out fp32 (+b2) -------
// Phase A: HALF-WAVE PER ROW (32 lanes x uint2 = 256 B row), 2 rows in flight per wave.

__global__ __launch_bounds__(256)
void fused2_kernel(const uint2* __restrict__ hs4, const int* __restrict__ rowptr,
                   const int* __restrict__ col, const float* __restrict__ dinv,
                   const unsigned short* __restrict__ w2f, const float* __restrict__ b2,
                   float* __restrict__ out, int n) {
    __shared__ unsigned int Atile[16][68];  // row-stride 68 uints (16B pad)
    int t = threadIdx.x;
    int wv = t >> 6, lane = t & 63;
    int tile = blockIdx.x;
    int half = lane >> 5, sl = lane & 31;

    // Phase A: 2 passes x (2 rows per wave, one per half-wave); lane sl holds feats 4sl..4sl+3
#pragma unroll
    for (int pass = 0; pass < 2; ++pass) {
        int r = wv * 4 + pass * 2 + half;
        int row = tile * 16 + r;
        float a0 = 0.0f, a1 = 0.0f, a2 = 0.0f, a3 = 0.0f;
        if (row < n) {
            int beg = rowptr[row];
            int end = rowptr[row + 1];
            float di = dinv[row];
            uint2 sp = hs4[(size_t)row * 32 + sl];
            a0 = bf_lo(sp.x); a1 = bf_hi(sp.x);
            a2 = bf_lo(sp.y); a3 = bf_hi(sp.y);
            int e = beg;
            for (; e + 7 < end; e += 8) {
                int c0 = col[e], c1 = col[e + 1], c2 = col[e + 2], c3 = col[e + 3];
                int c4 = col[e + 4], c5 = col[e + 5], c6 = col[e + 6], c7 = col[e + 7];
                uint2 p0 = hs4[(size_t)c0 * 32 + sl];
                uint2 p1 = hs4[(size_t)c1 * 32 + sl];
                uint2 p2 = hs4[(size_t)c2 * 32 + sl];
                uint2 p3 = hs4[(size_t)c3 * 32 + sl];
                uint2 p4 = hs4[(size_t)c4 * 32 + sl];
                uint2 p5 = hs4[(size_t)c5 * 32 + sl];
                uint2 p6 = hs4[(size_t)c6 * 32 + sl];
                uint2 p7 = hs4[(size_t)c7 * 32 + sl];
                a0 += bf_lo(p0.x); a1 += bf_hi(p0.x); a2 += bf_lo(p0.y); a3 += bf_hi(p0.y);
                a0 += bf_lo(p1.x); a1 += bf_hi(p1.x); a2 += bf_lo(p1.y); a3 += bf_hi(p1.y);
                a0 += bf_lo(p2.x); a1 += bf_hi(p2.x); a2 += bf_lo(p2.y); a3 += bf_hi(p2.y);
                a0 += bf_lo(p3.x); a1 += bf_hi(p3.x); a2 += bf_lo(p3.y); a3 += bf_hi(p3.y);
                a0 += bf_lo(p4.x); a1 += bf_hi(p4.x); a2 += bf_lo(p4.y); a3 += bf_hi(p4.y);
                a0 += bf_lo(p5.x); a1 += bf_hi(p5.x); a2 += bf_lo(p5.y); a3 += bf_hi(p5.y);
                a0 += bf_lo(p6.x); a1 += bf_hi(p6.x); a2 += bf_lo(p6.y); a3 += bf_hi(p6.y);
                a0 += bf_lo(p7.x); a1 += bf_hi(p7.x); a2 += bf_lo(p7.y); a3 += bf_hi(p7.y);
            }
            for (; e < end; ++e) {
                uint2 p = hs4[(size_t)col[e] * 32 + sl];
                a0 += bf_lo(p.x); a1 += bf_hi(p.x);
                a2 += bf_lo(p.y); a3 += bf_hi(p.y);
            }
            a0 *= di; a1 *= di; a2 *= di; a3 *= di;
        }
        Atile[r][2 * sl]     = pack2bf(a0, a1);
        Atile[r][2 * sl + 1] = pack2bf(a2, a3);
    }
    __syncthreads();

    // Phase B: wave wv computes cols [wv*32, wv*32+32) = c-frags {wv*2, wv*2+1}
    const short8v* bfr = (const short8v*)w2f;
    const unsigned int* ap = &Atile[0][0];
    short8v af[4];
#pragma unroll
    for (int kk = 0; kk < 4; ++kk) {
        af[kk] = *(const short8v*)(ap + (lane & 15) * 68 + kk * 16 + (lane >> 4) * 4);
    }
    f32x4 acc[2];
#pragma unroll
    for (int ci = 0; ci < 2; ++ci) acc[ci] = (f32x4){0.0f, 0.0f, 0.0f, 0.0f};
#pragma unroll
    for (int kk = 0; kk < 4; ++kk) {
#pragma unroll
        for (int ci = 0; ci < 2; ++ci) {
            int c = wv * 2 + ci;
            acc[ci] = __builtin_amdgcn_mfma_f32_16x16x32_bf16(af[kk], bfr[(c * 4 + kk) * 64 + lane],
                                                              acc[ci], 0, 0, 0);
        }
    }
    int colbase = lane & 15;
    int rowg = (lane >> 4) * 4;
#pragma unroll
    for (int ci = 0; ci < 2; ++ci) {
        int c = wv * 2 + ci;
        float bv = b2[c * 16 + colbase];
#pragma unroll
        for (int j = 0; j < 4; ++j) {
            int row = tile * 16 + rowg + j;
            if (row < n) {
                out[(size_t)row * 128 + c * 16 + colbase] = acc[ci][j] + bv;
            }
        }
    }
}

// ---------------- launch ----------------

extern "C" void kernel_launch(void* const* d_in, const int* in_sizes, int n_in,
                              void* d_out, int out_size, void* d_ws, size_t ws_size,
                              hipStream_t stream) {
    const float* z  = (const float*)d_in[0];
    const int*   ei = (const int*)d_in[1];
    const float* W1 = (const float*)d_in[2];
    const float* b1 = (const float*)d_in[3];
    const float* W2 = (const float*)d_in[4];
    const float* b2 = (const float*)d_in[5];
    float* out = (float*)d_out;

    int N = in_sizes[0] / 64;
    int E = in_sizes[1] / 2;
    const int* srcp = ei;
    const int* dstp = ei + E;

    char* w = (char*)d_ws;
    auto alloc = [&](size_t bytes) -> char* {
        char* p = w;
        w += (bytes + 255) & ~(size_t)255;
        return p;
    };
    int nb = (N + 255) / 256;  // 196 for N=50000 (must be <= 256)

    int*   rowptr = (int*)alloc((size_t)(N + 1) * 4);
    float* dinv   = (float*)alloc((size_t)N * 4);
    int*   bcur   = (int*)alloc((size_t)nb * 4);
    int*   col    = (int*)alloc((size_t)E * 4);
    unsigned int* tmp = (unsigned int*)alloc((size_t)nb * BCAP * 4);  // packed (src<<8)|(dst&255)
    unsigned int*   zsb = (unsigned int*)alloc((size_t)N * 64 * 2);   // bf16 zs = dinv*z (packed)
    unsigned short* hsb = (unsigned short*)alloc((size_t)N * 128 * 2);// bf16 hs = dinv*h
    unsigned short* w1f = (unsigned short*)alloc(8192 * 2);           // W1 frag-major bf16
    unsigned short* w2f = (unsigned short*)alloc(16384 * 2);          // W2 frag-major bf16

    int ntiles = (N + 15) / 16;  // 3125 for N=50000

    // 5 dispatches total
    prep_kernel<<<64, 256, 0, stream>>>(W1, W2, w1f, w2f, bcur, nb);
    partA_kernel<<<(E + 4095) / 4096, 1024, 0, stream>>>(srcp, dstp, bcur, tmp, E);
    bucket_build_kernel<<<nb, 256, 0, stream>>>(tmp, bcur, z, rowptr, dinv, col, zsb, N, nb, E);
    fused1_kernel<<<ntiles, 256, 0, stream>>>(zsb, rowptr, col, dinv, w1f, b1, hsb, N);
    fused2_kernel<<<ntiles, 256, 0, stream>>>((const uint2*)hsb, rowptr, col, dinv,
                                              w2f, b2, out, N);
}

// Round 18
// 104.864 us; speedup vs baseline: 1.6845x; 1.0823x over previous
//
#include <hip/hip_runtime.h>
#include <math.h>

using short8v = __attribute__((ext_vector_type(8))) short;
using f32x4   = __attribute__((ext_vector_type(4))) float;

constexpr int BCAP = 8192;  // per-bucket capacity (mean ~4081, >60 sigma headroom)

// ---------------- bf16 helpers ----------------

__device__ inline float bf_lo(unsigned int p) { return __uint_as_float(p << 16); }
__device__ inline float bf_hi(unsigned int p) { return __uint_as_float(p & 0xffff0000u); }
__device__ inline unsigned short f2bf(float f) {  // round-to-nearest-even
    unsigned int u = __float_as_uint(f);
    u += 0x7fffu + ((u >> 16) & 1u);
    return (unsigned short)(u >> 16);
}
__device__ inline unsigned int pack2bf(float a, float b) {
    return (unsigned int)f2bf(a) | ((unsigned int)f2bf(b) << 16);
}

// ------- prep: init bucket cursors + W1/W2 -> frag-major bf16 in global -------
// frag layout (per MFMA 16x16x32 B-operand): elem index e = ((c*KK+kk)*64 + l)*8 + j
// maps to W[kk*32 + (l>>4)*8 + j][c*16 + (l&15)].

__global__ __launch_bounds__(256)
void prep_kernel(const float* __restrict__ W1, const float* __restrict__ W2,
                 unsigned short* __restrict__ w1f, unsigned short* __restrict__ w2f,
                 int* __restrict__ bcur, int nb) {
    int i = blockIdx.x * 256 + threadIdx.x;
    if (i < nb) bcur[i] = i * BCAP;
    if (i < 8 * 2 * 64 * 8) {  // 8192 = K64 frags (KK=2)
        int j = i & 7, l = (i >> 3) & 63, rest = i >> 9;
        int kk = rest & 1, c = rest >> 1;
        int rk = kk * 32 + (l >> 4) * 8 + j;
        int cc = c * 16 + (l & 15);
        w1f[i] = f2bf(W1[rk * 128 + cc]);
    }
    if (i < 8 * 4 * 64 * 8) {  // 16384 = K128 frags (KK=4)
        int j = i & 7, l = (i >> 3) & 63, rest = i >> 9;
        int kk = rest & 3, c = rest >> 2;
        int rk = kk * 32 + (l >> 4) * 8 + j;
        int cc = c * 16 + (l & 15);
        w2f[i] = f2bf(W2[rk * 128 + cc]);
    }
}

// ---------------- partition: bucket edges by dst>>8; 4096 edges/block ----------------
// packed entry: (src << 8) | (dst & 255)   [valid: N < 65536]

__global__ __launch_bounds__(1024)
void partA_kernel(const int* __restrict__ src, const int* __restrict__ dst,
                  int* __restrict__ bcur, unsigned int* __restrict__ tmp, int E) {
    __shared__ int hist[256];
    __shared__ int chunk[256];
    int t = threadIdx.x;
    if (t < 256) hist[t] = 0;
    __syncthreads();
    int base = blockIdx.x * 4096;
    int s[4], d[4], bb[4], lr[4];
    bool val[4];
#pragma unroll
    for (int k = 0; k < 4; ++k) {
        int i = base + k * 1024 + t;
        val[k] = i < E;
        if (val[k]) {
            s[k] = src[i];
            d[k] = dst[i];
            bb[k] = d[k] >> 8;
            lr[k] = atomicAdd(&hist[bb[k]], 1);  // LDS: local rank in (block,bucket)
        }
    }
    __syncthreads();
    if (t < 256) {
        int c = hist[t];
        chunk[t] = (c > 0) ? atomicAdd(&bcur[t], c) : 0;
    }
    __syncthreads();
#pragma unroll
    for (int k = 0; k < 4; ++k) {
        if (val[k]) tmp[chunk[bb[k]] + lr[k]] = ((unsigned int)s[k] << 8) | (unsigned int)(d[k] & 255);
    }
}

// ------- bucket_build: folded bucket-scan + per-bucket CSR + dinv + prescaled z -------

__global__ __launch_bounds__(256)
void bucket_build_kernel(const unsigned int* __restrict__ tmp, const int* __restrict__ bcur,
                         const float* __restrict__ z, int* __restrict__ rowptr,
                         float* __restrict__ dinv, int* __restrict__ col,
                         unsigned int* __restrict__ zsb, int N, int nb, int E) {
    __shared__ int s[256];
    __shared__ int h[256];
    __shared__ int sc[256];
    __shared__ int cur[256];
    __shared__ float sdv[256];
    __shared__ int s_eb;
    int b = blockIdx.x;
    int t = threadIdx.x;
    // folded bscan: every block scans all bucket counts (196 ints, trivial)
    int cnt_t = (t < nb) ? (bcur[t] - t * BCAP) : 0;
    s[t] = cnt_t;
    __syncthreads();
    for (int off = 1; off < 256; off <<= 1) {
        int u = (t >= off) ? s[t - off] : 0;
        __syncthreads();
        s[t] += u;
        __syncthreads();
    }
    if (t == b) s_eb = s[t] - cnt_t;  // exclusive prefix for this bucket
    if (b == 0 && t == 0) rowptr[N] = E;
    h[t] = 0;
    __syncthreads();
    int eb = s_eb;
    int base = b * BCAP;
    int ecnt = bcur[b] - base;
    // per-node histogram
    for (int i = t; i < ecnt; i += 256) {
        atomicAdd(&h[tmp[base + i] & 255], 1);
    }
    __syncthreads();
    int v = h[t];
    sc[t] = v;
    __syncthreads();
    for (int off = 1; off < 256; off <<= 1) {
        int u = (t >= off) ? sc[t - off] : 0;
        __syncthreads();
        sc[t] += u;
        __syncthreads();
    }
    int excl = sc[t] - v;
    int nd = b * 256 + t;
    float dv = rsqrtf((float)v + 1.0f);  // degree incl. self-loop
    if (nd < N) {
        rowptr[nd] = eb + excl;
        dinv[nd] = dv;
    }
    sdv[t] = dv;
    cur[t] = excl;
    __syncthreads();
    // scatter col (LDS cursors, contiguous window)
    for (int i = t; i < ecnt; i += 256) {
        unsigned int e = tmp[base + i];
        int lpos = atomicAdd(&cur[e & 255], 1);
        col[eb + lpos] = (int)(e >> 8);
    }
    // prescale this block's 256 z-rows: zs = bf16(dinv * z), packed pairs (32 uints/row)
    int nd0 = b * 256;
    for (int idx = t; idx < 256 * 32; idx += 256) {
        int row = idx >> 5;
        int p = idx & 31;
        int node = nd0 + row;
        if (node < N) {
            float2 zv = ((const float2*)z)[(size_t)node * 32 + p];
            float d = sdv[row];
            zsb[(size_t)node * 32 + p] = pack2bf(d * zv.x, d * zv.y);
        }
    }
}

// ------- fused1: [agg64 over zs] -> LDS A-tile -> MFMA W1 -> hs = bf16(dinv.*relu(.+b1)) -------
// 1 tile (16 rows) per block. Phase A: QUARTER-WAVE PER ROW (16 lanes x uint2 = 128 B row),
// 4 rows in flight per wave x 8-edge unroll; single pass covers all 16 rows.
// Phase B: 16x32 col slice per wave.
// mfma_f32_16x16x32_bf16 frags: A lane l: row=l&15, k=(l>>4)*8+j ; B: col=l&15, k=(l>>4)*8+j ;
// C/D: col=l&15, row=(l>>4)*4+j  [m89-verified].

__global__ __launch_bounds__(256)
void fused1_kernel(const uint2* __restrict__ zs4, const int* __restrict__ rowptr,
                   const int* __restrict__ col, const float* __restrict__ dinv,
                   const unsigned short* __restrict__ w1f, const float* __restrict__ b1,
                   unsigned short* __restrict__ hsb, int n) {
    __shared__ unsigned int Atile[16][36];  // row-stride 36 uints (16B pad -> 2-way banks)
    int t = threadIdx.x;
    int wv = t >> 6, lane = t & 63;
    int tile = blockIdx.x;
    int quarter = lane >> 4, ql = lane & 15;  // lane ql holds feats 4ql..4ql+3

    // Phase A: one row per quarter-wave (4 rows in flight per wave)
    {
        int r = wv * 4 + quarter;
        int row = tile * 16 + r;
        float a0 = 0.0f, a1 = 0.0f, a2 = 0.0f, a3 = 0.0f;
        if (row < n) {
            int beg = rowptr[row];
            int end = rowptr[row + 1];
            float di = dinv[row];
            uint2 sp = zs4[(size_t)row * 16 + ql];
            a0 = bf_lo(sp.x); a1 = bf_hi(sp.x);
            a2 = bf_lo(sp.y); a3 = bf_hi(sp.y);
            int e = beg;
            for (; e + 7 < end; e += 8) {
                int c0 = col[e], c1 = col[e + 1], c2 = col[e + 2], c3 = col[e + 3];
                int c4 = col[e + 4], c5 = col[e + 5], c6 = col[e + 6], c7 = col[e + 7];
                uint2 p0 = zs4[(size_t)c0 * 16 + ql];
                uint2 p1 = zs4[(size_t)c1 * 16 + ql];
                uint2 p2 = zs4[(size_t)c2 * 16 + ql];
                uint2 p3 = zs4[(size_t)c3 * 16 + ql];
                uint2 p4 = zs4[(size_t)c4 * 16 + ql];
                uint2 p5 = zs4[(size_t)c5 * 16 + ql];
                uint2 p6 = zs4[(size_t)c6 * 16 + ql];
                uint2 p7 = zs4[(size_t)c7 * 16 + ql];
                a0 += bf_lo(p0.x); a1 += bf_hi(p0.x); a2 += bf_lo(p0.y); a3 += bf_hi(p0.y);
                a0 += bf_lo(p1.x); a1 += bf_hi(p1.x); a2 += bf_lo(p1.y); a3 += bf_hi(p1.y);
                a0 += bf_lo(p2.x); a1 += bf_hi(p2.x); a2 += bf_lo(p2.y); a3 += bf_hi(p2.y);
                a0 += bf_lo(p3.x); a1 += bf_hi(p3.x); a2 += bf_lo(p3.y); a3 += bf_hi(p3.y);
                a0 += bf_lo(p4.x); a1 += bf_hi(p4.x); a2 += bf_lo(p4.y); a3 += bf_hi(p4.y);
                a0 += bf_lo(p5.x); a1 += bf_hi(p5.x); a2 += bf_lo(p5.y); a3 += bf_hi(p5.y);
                a0 += bf_lo(p6.x); a1 += bf_hi(p6.x); a2 += bf_lo(p6.y); a3 += bf_hi(p6.y);
                a0 += bf_lo(p7.x); a1 += bf_hi(p7.x); a2 += bf_lo(p7.y); a3 += bf_hi(p7.y);
            }
            for (; e < end; ++e) {
                uint2 p = zs4[(size_t)col[e] * 16 + ql];
                a0 += bf_lo(p.x); a1 += bf_hi(p.x);
                a2 += bf_lo(p.y); a3 += bf_hi(p.y);
            }
            a0 *= di; a1 *= di; a2 *= di; a3 *= di;
        }
        Atile[r][2 * ql]     = pack2bf(a0, a1);
        Atile[r][2 * ql + 1] = pack2bf(a2, a3);
    }
    __syncthreads();

    // Phase B: wave wv computes cols [wv*32, wv*32+32) = c-frags {wv*2, wv*2+1}
    const short8v* bfr = (const short8v*)w1f;
    const unsigned int* ap = &Atile[0][0];
    short8v af[2];
#pragma unroll
    for (int kk = 0; kk < 2; ++kk) {
        af[kk] = *(const short8v*)(ap + (lane & 15) * 36 + kk * 16 + (lane >> 4) * 4);
    }
    f32x4 acc[2];
#pragma unroll
    for (int ci = 0; ci < 2; ++ci) acc[ci] = (f32x4){0.0f, 0.0f, 0.0f, 0.0f};
#pragma unroll
    for (int kk = 0; kk < 2; ++kk) {
#pragma unroll
        for (int ci = 0; ci < 2; ++ci) {
            int c = wv * 2 + ci;
            acc[ci] = __builtin_amdgcn_mfma_f32_16x16x32_bf16(af[kk], bfr[(c * 2 + kk) * 64 + lane],
                                                              acc[ci], 0, 0, 0);
        }
    }
    int colbase = lane & 15;
    int rowg = (lane >> 4) * 4;
    float dvj[4];
#pragma unroll
    for (int j = 0; j < 4; ++j) {
        int row = tile * 16 + rowg + j;
        dvj[j] = (row < n) ? dinv[row] : 1.0f;
    }
#pragma unroll
    for (int ci = 0; ci < 2; ++ci) {
        int c = wv * 2 + ci;
        float bv = b1[c * 16 + colbase];
#pragma unroll
        for (int j = 0; j < 4; ++j) {
            int row = tile * 16 + rowg + j;
            if (row < n) {
                float v = fmaxf(acc[ci][j] + bv, 0.0f) * dvj[j];
                hsb[(size_t)row * 128 + c * 16 + colbase] = f2bf(v);
            }
        }
    }
}

// ------- fused2: [agg128 over hs] -> LDS A-tile -> MFMA W2 -> out fp32 (+b2) -------
// Phase A: QUARTER-WAVE PER ROW (16 lanes x uint4 = 256 B row), 4 rows in flight per wave,
// 4-edge unroll (16 uint4 in flight). Lane ql holds feats 8ql..8ql+7.

__global__ __launch_bounds__(256)
void fused2_kernel(const uint4* __restrict__ hs8, const int* __restrict__ rowptr,
                   const int* __restrict__ col, const float* __restrict__ dinv,
                   const unsigned short* __restrict__ w2f, const float* __restrict__ b2,
                   float* __restrict__ out, int n) {
    __shared__ unsigned int Atile[16][68];  // row-stride 68 uints (16B pad)
    int t = threadIdx.x;
    int wv = t >> 6, lane = t & 63;
    int tile = blockIdx.x;
    int quarter = lane >> 4, ql = lane & 15;

    // Phase A: one row per quarter-wave
    {
        int r = wv * 4 + quarter;
        int row = tile * 16 + r;
        float a0 = 0.0f, a1 = 0.0f, a2 = 0.0f, a3 = 0.0f;
        float a4 = 0.0f, a5 = 0.0f, a6 = 0.0f, a7 = 0.0f;
        if (row < n) {
            int beg = rowptr[row];
            int end = rowptr[row + 1];
            float di = dinv[row];
            uint4 sp = hs8[(size_t)row * 16 + ql];
            a0 = bf_lo(sp.x); a1 = bf_hi(sp.x);
            a2 = bf_lo(sp.y); a3 = bf_hi(sp.y);
            a4 = bf_lo(sp.z); a5 = bf_hi(sp.z);
            a6 = bf_lo(sp.w); a7 = bf_hi(sp.w);
            int e = beg;
            for (; e + 3 < end; e += 4) {
                int c0 = col[e], c1 = col[e + 1], c2 = col[e + 2], c3 = col[e + 3];
                uint4 p0 = hs8[(size_t)c0 * 16 + ql];
                uint4 p1 = hs8[(size_t)c1 * 16 + ql];
                uint4 p2 = hs8[(size_t)c2 * 16 + ql];
                uint4 p3 = hs8[(size_t)c3 * 16 + ql];
                a0 += bf_lo(p0.x); a1 += bf_hi(p0.x); a2 += bf_lo(p0.y); a3 += bf_hi(p0.y);
                a4 += bf_lo(p0.z); a5 += bf_hi(p0.z); a6 += bf_lo(p0.w); a7 += bf_hi(p0.w);
                a0 += bf_lo(p1.x); a1 += bf_hi(p1.x); a2 += bf_lo(p1.y); a3 += bf_hi(p1.y);
                a4 += bf_lo(p1.z); a5 += bf_hi(p1.z); a6 += bf_lo(p1.w); a7 += bf_hi(p1.w);
                a0 += bf_lo(p2.x); a1 += bf_hi(p2.x); a2 += bf_lo(p2.y); a3 += bf_hi(p2.y);
                a4 += bf_lo(p2.z); a5 += bf_hi(p2.z); a6 += bf_lo(p2.w); a7 += bf_hi(p2.w);
                a0 += bf_lo(p3.x); a1 += bf_hi(p3.x); a2 += bf_lo(p3.y); a3 += bf_hi(p3.y);
                a4 += bf_lo(p3.z); a5 += bf_hi(p3.z); a6 += bf_lo(p3.w); a7 += bf_hi(p3.w);
            }
            for (; e < end; ++e) {
                uint4 p = hs8[(size_t)col[e] * 16 + ql];
                a0 += bf_lo(p.x); a1 += bf_hi(p.x); a2 += bf_lo(p.y); a3 += bf_hi(p.y);
                a4 += bf_lo(p.z); a5 += bf_hi(p.z); a6 += bf_lo(p.w); a7 += bf_hi(p.w);
            }
            a0 *= di; a1 *= di; a2 *= di; a3 *= di;
            a4 *= di; a5 *= di; a6 *= di; a7 *= di;
        }
        Atile[r][4 * ql]     = pack2bf(a0, a1);
        Atile[r][4 * ql + 1] = pack2bf(a2, a3);
        Atile[r][4 * ql + 2] = pack2bf(a4, a5);
        Atile[r][4 * ql + 3] = pack2bf(a6, a7);
    }
    __syncthreads();

    // Phase B: wave wv computes cols [wv*32, wv*32+32) = c-frags {wv*2, wv*2+1}
    const short8v* bfr = (const short8v*)w2f;
    const unsigned int* ap = &Atile[0][0];
    short8v af[4];
#pragma unroll
    for (int kk = 0; kk < 4; ++kk) {
        af[kk] = *(const short8v*)(ap + (lane & 15) * 68 + kk * 16 + (lane >> 4) * 4);
    }
    f32x4 acc[2];
#pragma unroll
    for (int ci = 0; ci < 2; ++ci) acc[ci] = (f32x4){0.0f, 0.0f, 0.0f, 0.0f};
#pragma unroll
    for (int kk = 0; kk < 4; ++kk) {
#pragma unroll
        for (int ci = 0; ci < 2; ++ci) {
            int c = wv * 2 + ci;
            acc[ci] = __builtin_amdgcn_mfma_f32_16x16x32_bf16(af[kk], bfr[(c * 4 + kk) * 64 + lane],
                                                              acc[ci], 0, 0, 0);
        }
    }
    int colbase = lane & 15;
    int rowg = (lane >> 4) * 4;
#pragma unroll
    for (int ci = 0; ci < 2; ++ci) {
        int c = wv * 2 + ci;
        float bv = b2[c * 16 + colbase];
#pragma unroll
        for (int j = 0; j < 4; ++j) {
            int row = tile * 16 + rowg + j;
            if (row < n) {
                out[(size_t)row * 128 + c * 16 + colbase] = acc[ci][j] + bv;
            }
        }
    }
}

// ---------------- launch ----------------

extern "C" void kernel_launch(void* const* d_in, const int* in_sizes, int n_in,
                              void* d_out, int out_size, void* d_ws, size_t ws_size,
                              hipStream_t stream) {
    const float* z  = (const float*)d_in[0];
    const int*   ei = (const int*)d_in[1];
    const float* W1 = (const float*)d_in[2];
    const float* b1 = (const float*)d_in[3];
    const float* W2 = (const float*)d_in[4];
    const float* b2 = (const float*)d_in[5];
    float* out = (float*)d_out;

    int N = in_sizes[0] / 64;
    int E = in_sizes[1] / 2;
    const int* srcp = ei;
    const int* dstp = ei + E;

    char* w = (char*)d_ws;
    auto alloc = [&](size_t bytes) -> char* {
        char* p = w;
        w += (bytes + 255) & ~(size_t)255;
        return p;
    };
    int nb = (N + 255) / 256;  // 196 for N=50000 (must be <= 256)

    int*   rowptr = (int*)alloc((size_t)(N + 1) * 4);
    float* dinv   = (float*)alloc((size_t)N * 4);
    int*   bcur   = (int*)alloc((size_t)nb * 4);
    int*   col    = (int*)alloc((size_t)E * 4);
    unsigned int* tmp = (unsigned int*)alloc((size_t)nb * BCAP * 4);  // packed (src<<8)|(dst&255)
    unsigned int*   zsb = (unsigned int*)alloc((size_t)N * 64 * 2);   // bf16 zs = dinv*z (packed)
    unsigned short* hsb = (unsigned short*)alloc((size_t)N * 128 * 2);// bf16 hs = dinv*h
    unsigned short* w1f = (unsigned short*)alloc(8192 * 2);           // W1 frag-major bf16
    unsigned short* w2f = (unsigned short*)alloc(16384 * 2);          // W2 frag-major bf16

    int ntiles = (N + 15) / 16;  // 3125 for N=50000

    // 5 dispatches total
    prep_kernel<<<64, 256, 0, stream>>>(W1, W2, w1f, w2f, bcur, nb);
    partA_kernel<<<(E + 4095) / 4096, 1024, 0, stream>>>(srcp, dstp, bcur, tmp, E);
    bucket_build_kernel<<<nb, 256, 0, stream>>>(tmp, bcur, z, rowptr, dinv, col, zsb, N, nb, E);
    fused1_kernel<<<ntiles, 256, 0, stream>>>((const uint2*)zsb, rowptr, col, dinv, w1f, b1, hsb, N);
    fused2_kernel<<<ntiles, 256, 0, stream>>>((const uint4*)hsb, rowptr, col, dinv,
                                              w2f, b2, out, N);
}